// Round 1
// baseline (1886.542 us; speedup 1.0000x reference)
//
#include <hip/hip_runtime.h>

#define BB 64
#define LL 2048
#define TT 128

// ---------------- numerator: gold path score per batch ----------------
__global__ __launch_bounds__(256) void crf_num_kernel(
    const float* __restrict__ em, const int* __restrict__ tgt,
    const int* __restrict__ mask, const float* __restrict__ start,
    const float* __restrict__ endt, const float* __restrict__ trans,
    float* __restrict__ num_out)
{
    const int b = blockIdx.x;
    const int t = threadIdx.x;
    const int wave = t >> 6, lane = t & 63;
    const float* emb = em + (size_t)b * LL * TT;
    const int* tb = tgt + (size_t)b * LL;
    const int* mb = mask + (size_t)b * LL;

    float acc = 0.f;
    int msum = 0;
    for (int l = t; l < LL; l += 256) {
        int mv = mb[l];
        msum += mv;
        if (l >= 1 && mv > 0) {
            int tp = tb[l - 1], tc = tb[l];
            acc += trans[tp * TT + tc] + emb[(size_t)l * TT + tc];
        }
    }
    __shared__ float sacc[4];
    __shared__ int smsum[4];
    #pragma unroll
    for (int off = 32; off; off >>= 1) {
        acc += __shfl_xor(acc, off);
        msum += __shfl_xor(msum, off);
    }
    if (lane == 0) { sacc[wave] = acc; smsum[wave] = msum; }
    __syncthreads();
    if (t == 0) {
        float tot = sacc[0] + sacc[1] + sacc[2] + sacc[3];
        int total_mask = smsum[0] + smsum[1] + smsum[2] + smsum[3];
        int t0 = tb[0];
        tot += start[t0] + emb[t0];           // first-step score
        int se = total_mask - 1;              // seq_ends
        int lt = tb[se];
        tot += endt[lt];
        num_out[b] = tot;
    }
}

// ---------------- denominator: forward algorithm, 1 block per batch ----------------
// score'[j] = em[i][j] + m + c_j + log( sum_k exp(s[k]-m) * E[k][j] )
// with E[k][j] = exp(trans[k][j] - c_j) precomputed in registers (column j per thread).
__global__ __launch_bounds__(128) void crf_forward_kernel(
    const float* __restrict__ em, const int* __restrict__ mask,
    const float* __restrict__ start, const float* __restrict__ endt,
    const float* __restrict__ trans, float* __restrict__ den_out)
{
    const int b = blockIdx.x;
    const int j = threadIdx.x;      // 0..127, owns tag j
    const int wave = j >> 6;
    const int lane = j & 63;

    __shared__ __align__(16) float p_sh[TT];
    __shared__ float red[2];
    __shared__ float red2[2];

    // column max + E column in registers
    float cj = -1e30f;
    for (int k = 0; k < TT; ++k) cj = fmaxf(cj, trans[k * TT + j]);
    float Ecol[TT];
    #pragma unroll
    for (int k = 0; k < TT; ++k) Ecol[k] = __expf(trans[k * TT + j] - cj);

    const float* emb = em + (size_t)b * LL * TT;
    const int* mb = mask + (size_t)b * LL;

    float s = start[j] + emb[j];

    // publish initial block max
    {
        float m = s;
        #pragma unroll
        for (int off = 32; off; off >>= 1) m = fmaxf(m, __shfl_xor(m, off));
        if (lane == 0) red[wave] = m;
    }
    __syncthreads();   // barrier A

    // prefetch step 1
    float em_next = emb[TT + j];
    int msk_next = mb[1];

    for (int i = 1; i < LL; ++i) {
        const float em_cur = em_next;
        const int msk = msk_next;
        if (i + 1 < LL) {
            em_next = emb[(size_t)(i + 1) * TT + j];
            msk_next = mb[i + 1];
        }

        const float m = fmaxf(red[0], red[1]);
        p_sh[j] = __expf(s - m);
        __syncthreads();   // barrier B: p_sh visible

        float acc = 0.f;
        const float4* pv = (const float4*)p_sh;
        #pragma unroll
        for (int kk = 0; kk < TT / 4; ++kk) {
            float4 pq = pv[kk];
            acc = fmaf(pq.x, Ecol[4 * kk + 0], acc);
            acc = fmaf(pq.y, Ecol[4 * kk + 1], acc);
            acc = fmaf(pq.z, Ecol[4 * kk + 2], acc);
            acc = fmaf(pq.w, Ecol[4 * kk + 3], acc);
        }
        const float snew = em_cur + m + cj + __logf(acc);
        s = (msk > 0) ? snew : s;

        // publish next block max (also fences p_sh reads via barrier A)
        float mm = s;
        #pragma unroll
        for (int off = 32; off; off >>= 1) mm = fmaxf(mm, __shfl_xor(mm, off));
        if (lane == 0) red[wave] = mm;
        __syncthreads();   // barrier A for next iteration
    }

    // den = logsumexp_j(s[j] + end[j])
    float v = s + endt[j];
    float m2 = v;
    #pragma unroll
    for (int off = 32; off; off >>= 1) m2 = fmaxf(m2, __shfl_xor(m2, off));
    if (lane == 0) red2[wave] = m2;
    __syncthreads();
    m2 = fmaxf(red2[0], red2[1]);
    float e = __expf(v - m2);
    #pragma unroll
    for (int off = 32; off; off >>= 1) e += __shfl_xor(e, off);
    if (lane == 0) red[wave] = e;
    __syncthreads();
    if (j == 0) den_out[b] = m2 + __logf(red[0] + red[1]);
}

// ---------------- final: out = sum_b (den_b - num_b) ----------------
__global__ void crf_final_kernel(const float* __restrict__ den,
                                 const float* __restrict__ num,
                                 float* __restrict__ out)
{
    int t = threadIdx.x;   // 64 threads == BB
    float v = den[t] - num[t];
    #pragma unroll
    for (int off = 32; off; off >>= 1) v += __shfl_xor(v, off);
    if (t == 0) out[0] = v;
}

extern "C" void kernel_launch(void* const* d_in, const int* in_sizes, int n_in,
                              void* d_out, int out_size, void* d_ws, size_t ws_size,
                              hipStream_t stream)
{
    const float* em    = (const float*)d_in[0];   // [B,L,T] f32
    const int*   tgt   = (const int*)d_in[1];     // [B,L]
    const int*   mask  = (const int*)d_in[2];     // [B,L]
    const float* start = (const float*)d_in[3];   // [T]
    const float* endt  = (const float*)d_in[4];   // [T]
    const float* trans = (const float*)d_in[5];   // [T,T]
    float* out = (float*)d_out;

    float* den = (float*)d_ws;        // BB floats
    float* num = den + BB;            // BB floats

    crf_num_kernel<<<BB, 256, 0, stream>>>(em, tgt, mask, start, endt, trans, num);
    crf_forward_kernel<<<BB, 128, 0, stream>>>(em, mask, start, endt, trans, den);
    crf_final_kernel<<<1, 64, 0, stream>>>(den, num, out);
}

// Round 2
// 1272.583 us; speedup vs baseline: 1.4825x; 1.4825x over previous
//
#include <hip/hip_runtime.h>

#define BB 64
#define LL 2048
#define TT 128
#define RS 4   // rescale period (deterministic, data-independent)

typedef float v2f __attribute__((ext_vector_type(2)));

// ---------------- numerator: gold path score per batch ----------------
__global__ __launch_bounds__(256) void crf_num_kernel(
    const float* __restrict__ em, const int* __restrict__ tgt,
    const int* __restrict__ mask, const float* __restrict__ start,
    const float* __restrict__ endt, const float* __restrict__ trans,
    float* __restrict__ num_out)
{
    const int b = blockIdx.x;
    const int t = threadIdx.x;
    const int wave = t >> 6, lane = t & 63;
    const float* emb = em + (size_t)b * LL * TT;
    const int* tb = tgt + (size_t)b * LL;
    const int* mb = mask + (size_t)b * LL;

    float acc = 0.f;
    int msum = 0;
    for (int l = t; l < LL; l += 256) {
        int mv = mb[l];
        msum += mv;
        if (l >= 1 && mv > 0) {
            int tp = tb[l - 1], tc = tb[l];
            acc += trans[tp * TT + tc] + emb[(size_t)l * TT + tc];
        }
    }
    __shared__ float sacc[4];
    __shared__ int smsum[4];
    #pragma unroll
    for (int off = 32; off; off >>= 1) {
        acc += __shfl_xor(acc, off);
        msum += __shfl_xor(msum, off);
    }
    if (lane == 0) { sacc[wave] = acc; smsum[wave] = msum; }
    __syncthreads();
    if (t == 0) {
        float tot = sacc[0] + sacc[1] + sacc[2] + sacc[3];
        int total_mask = smsum[0] + smsum[1] + smsum[2] + smsum[3];
        int t0 = tb[0];
        tot += start[t0] + emb[t0];           // first-step score
        int se = total_mask - 1;              // seq_ends
        int lt = tb[se];
        tot += endt[lt];
        num_out[b] = tot;
    }
}

// ---------------- denominator: forward algorithm, 1 block per batch ----------------
// s'[j] = em[i][j] + m + c_j + log( sum_k exp(s[k]-m) * E[k][j] ),
// E[k][j] = exp(trans[k][j] - c_j) held in VGPRs (launch_bounds(128,1) -> no spill).
// m rescaled only every RS steps (drift <= RS*(log T + em) << 88, exp-safe).
__global__ __launch_bounds__(128, 1) void crf_forward_kernel(
    const float* __restrict__ em, const int* __restrict__ mask,
    const float* __restrict__ start, const float* __restrict__ endt,
    const float* __restrict__ trans, float* __restrict__ den_out)
{
    const int b = blockIdx.x;
    const int j = threadIdx.x;      // 0..127, owns tag j
    const int wave = j >> 6;
    const int lane = j & 63;

    __shared__ __align__(16) float p_sh[2][TT];   // double-buffered
    __shared__ int mask_sh[LL];
    __shared__ float red[2];
    __shared__ float red2[2];

    const float* emb = em + (size_t)b * LL * TT;
    const int* mb = mask + (size_t)b * LL;

    // preload mask into LDS (broadcast reads later, no HBM on critical path)
    for (int l = j; l < LL; l += TT) mask_sh[l] = mb[l];

    // column max + E column in registers as float2 pairs
    float cj = -1e30f;
    for (int k = 0; k < TT; ++k) cj = fmaxf(cj, trans[k * TT + j]);
    v2f Ecol[TT / 2];
    #pragma unroll
    for (int k2 = 0; k2 < TT / 2; ++k2) {
        v2f e;
        e.x = __expf(trans[(2 * k2 + 0) * TT + j] - cj);
        e.y = __expf(trans[(2 * k2 + 1) * TT + j] - cj);
        Ecol[k2] = e;
    }

    float s = start[j] + emb[j];

    // initial block max -> m  (also fences mask_sh stores)
    {
        float mm = s;
        #pragma unroll
        for (int off = 32; off; off >>= 1) mm = fmaxf(mm, __shfl_xor(mm, off));
        if (lane == 0) red[wave] = mm;
    }
    __syncthreads();
    float m = fmaxf(red[0], red[1]);

    // 4-deep rolling prefetch of emission rows (named regs, compile-time indexed)
    float emA = emb[(size_t)1 * TT + j];
    float emB = emb[(size_t)2 * TT + j];
    float emC = emb[(size_t)3 * TT + j];
    float emD = emb[(size_t)4 * TT + j];

    for (int i = 1; i < LL; ++i) {
        const float em_cur = emA;
        emA = emB; emB = emC; emC = emD;
        if (i + 4 < LL) emD = emb[(size_t)(i + 4) * TT + j];

        const int buf = i & 1;
        p_sh[buf][j] = __expf(s - m);
        __syncthreads();   // B1: p visible (also orders reuse of this buffer, 2 steps apart)

        const float4* pv = (const float4*)p_sh[buf];
        v2f acc0 = {0.f, 0.f}, acc1 = {0.f, 0.f}, acc2 = {0.f, 0.f}, acc3 = {0.f, 0.f};
        #pragma unroll
        for (int q = 0; q < TT / 4; ++q) {          // 32 float4 loads, 64 packed FMAs
            float4 pq = pv[q];
            v2f plo = {pq.x, pq.y};
            v2f phi = {pq.z, pq.w};
            if ((q & 1) == 0) {
                acc0 = __builtin_elementwise_fma(plo, Ecol[2 * q + 0], acc0);
                acc1 = __builtin_elementwise_fma(phi, Ecol[2 * q + 1], acc1);
            } else {
                acc2 = __builtin_elementwise_fma(plo, Ecol[2 * q + 0], acc2);
                acc3 = __builtin_elementwise_fma(phi, Ecol[2 * q + 1], acc3);
            }
        }
        v2f accv = (acc0 + acc2) + (acc1 + acc3);
        const float acc = accv.x + accv.y;

        const int msk = mask_sh[i];
        const float snew = em_cur + m + cj + __logf(acc);
        s = (msk > 0) ? snew : s;

        if ((i & (RS - 1)) == 0) {
            // publish new block max; extra barrier only on these steps
            float mm = s;
            #pragma unroll
            for (int off = 32; off; off >>= 1) mm = fmaxf(mm, __shfl_xor(mm, off));
            if (lane == 0) red[wave] = mm;
            __syncthreads();   // B2: red visible
            m = fmaxf(red[0], red[1]);   // used consistently starting next step
        }
    }

    // den = logsumexp_j(s[j] + end[j])
    float v = s + endt[j];
    float m2 = v;
    #pragma unroll
    for (int off = 32; off; off >>= 1) m2 = fmaxf(m2, __shfl_xor(m2, off));
    if (lane == 0) red2[wave] = m2;
    __syncthreads();
    m2 = fmaxf(red2[0], red2[1]);
    float e = __expf(v - m2);
    #pragma unroll
    for (int off = 32; off; off >>= 1) e += __shfl_xor(e, off);
    if (lane == 0) red[wave] = e;
    __syncthreads();
    if (j == 0) den_out[b] = m2 + __logf(red[0] + red[1]);
}

// ---------------- final: out = sum_b (den_b - num_b) ----------------
__global__ void crf_final_kernel(const float* __restrict__ den,
                                 const float* __restrict__ num,
                                 float* __restrict__ out)
{
    int t = threadIdx.x;   // 64 threads == BB
    float v = den[t] - num[t];
    #pragma unroll
    for (int off = 32; off; off >>= 1) v += __shfl_xor(v, off);
    if (t == 0) out[0] = v;
}

extern "C" void kernel_launch(void* const* d_in, const int* in_sizes, int n_in,
                              void* d_out, int out_size, void* d_ws, size_t ws_size,
                              hipStream_t stream)
{
    const float* em    = (const float*)d_in[0];   // [B,L,T] f32
    const int*   tgt   = (const int*)d_in[1];     // [B,L]
    const int*   mask  = (const int*)d_in[2];     // [B,L]
    const float* start = (const float*)d_in[3];   // [T]
    const float* endt  = (const float*)d_in[4];   // [T]
    const float* trans = (const float*)d_in[5];   // [T,T]
    float* out = (float*)d_out;

    float* den = (float*)d_ws;        // BB floats
    float* num = den + BB;            // BB floats

    crf_num_kernel<<<BB, 256, 0, stream>>>(em, tgt, mask, start, endt, trans, num);
    crf_forward_kernel<<<BB, 128, 0, stream>>>(em, mask, start, endt, trans, den);
    crf_final_kernel<<<1, 64, 0, stream>>>(den, num, out);
}

// Round 3
// 1265.471 us; speedup vs baseline: 1.4908x; 1.0056x over previous
//
#include <hip/hip_runtime.h>

#define BB 64
#define LL 2048
#define TT 128

typedef float v4f __attribute__((ext_vector_type(4)));

// ---------------- numerator: gold path score per batch ----------------
__global__ __launch_bounds__(256) void crf_num_kernel(
    const float* __restrict__ em, const int* __restrict__ tgt,
    const int* __restrict__ mask, const float* __restrict__ start,
    const float* __restrict__ endt, const float* __restrict__ trans,
    float* __restrict__ num_out)
{
    const int b = blockIdx.x;
    const int t = threadIdx.x;
    const int wave = t >> 6, lane = t & 63;
    const float* emb = em + (size_t)b * LL * TT;
    const int* tb = tgt + (size_t)b * LL;
    const int* mb = mask + (size_t)b * LL;

    float acc = 0.f;
    int msum = 0;
    for (int l = t; l < LL; l += 256) {
        int mv = mb[l];
        msum += mv;
        if (l >= 1 && mv > 0) {
            int tp = tb[l - 1], tc = tb[l];
            acc += trans[tp * TT + tc] + emb[(size_t)l * TT + tc];
        }
    }
    __shared__ float sacc[4];
    __shared__ int smsum[4];
    #pragma unroll
    for (int off = 32; off; off >>= 1) {
        acc += __shfl_xor(acc, off);
        msum += __shfl_xor(msum, off);
    }
    if (lane == 0) { sacc[wave] = acc; smsum[wave] = msum; }
    __syncthreads();
    if (t == 0) {
        float tot = sacc[0] + sacc[1] + sacc[2] + sacc[3];
        int total_mask = smsum[0] + smsum[1] + smsum[2] + smsum[3];
        int t0 = tb[0];
        tot += start[t0] + emb[t0];
        int se = total_mask - 1;
        int lt = tb[se];
        tot += endt[lt];
        num_out[b] = tot;
    }
}

// ---------------- denominator: forward algorithm, 1 block per batch ----------------
// s'[j] = em[i][j] + m + c_j + log( sum_k exp(s[k]-m) * E[k][j] ),
// E[k][j] = exp(trans[k][j]-c_j) in 32 NAMED float4 regs (no alloca -> no scratch).
// m_i = s_{i-2}[0] (lag-2 broadcast offset; fenced by the regular barrier, no reduce).
__global__ __launch_bounds__(128, 1) void crf_forward_kernel(
    const float* __restrict__ em, const int* __restrict__ mask,
    const float* __restrict__ start, const float* __restrict__ endt,
    const float* __restrict__ trans, float* __restrict__ den_out)
{
    const int b = blockIdx.x;
    const int j = threadIdx.x;      // 0..127, owns tag j
    const int wave = j >> 6;
    const int lane = j & 63;

    __shared__ __align__(16) float p_sh[2][TT];   // double-buffered
    __shared__ float s0_sh[2];                    // lag-2 offset slots
    __shared__ int mask_sh[LL];
    __shared__ float red[2];
    __shared__ float red2[2];

    const float* emb = em + (size_t)b * LL * TT;
    const int* mb = mask + (size_t)b * LL;

    for (int l = j; l < LL; l += TT) mask_sh[l] = mb[l];

    float cj = -1e30f;
    for (int k = 0; k < TT; ++k) cj = fmaxf(cj, trans[k * TT + j]);

#define EINIT(n) const v4f E##n = { \
    __expf(trans[(4*(n)+0) * TT + j] - cj), \
    __expf(trans[(4*(n)+1) * TT + j] - cj), \
    __expf(trans[(4*(n)+2) * TT + j] - cj), \
    __expf(trans[(4*(n)+3) * TT + j] - cj) };
    EINIT(0)  EINIT(1)  EINIT(2)  EINIT(3)
    EINIT(4)  EINIT(5)  EINIT(6)  EINIT(7)
    EINIT(8)  EINIT(9)  EINIT(10) EINIT(11)
    EINIT(12) EINIT(13) EINIT(14) EINIT(15)
    EINIT(16) EINIT(17) EINIT(18) EINIT(19)
    EINIT(20) EINIT(21) EINIT(22) EINIT(23)
    EINIT(24) EINIT(25) EINIT(26) EINIT(27)
    EINIT(28) EINIT(29) EINIT(30) EINIT(31)
#undef EINIT

    float s = start[j] + emb[j];
    if (j == 0) { s0_sh[0] = s; s0_sh[1] = s; }
    __syncthreads();   // fences mask_sh + s0_sh init

    // 4-deep rolling prefetch of emission rows
    float emA = emb[(size_t)1 * TT + j];
    float emB = emb[(size_t)2 * TT + j];
    float emC = emb[(size_t)3 * TT + j];
    float emD = emb[(size_t)4 * TT + j];

    #pragma unroll 2
    for (int i = 1; i < LL; ++i) {
        const float em_cur = emA;
        emA = emB; emB = emC; emC = emD;
        if (i + 4 < LL) emD = emb[(size_t)(i + 4) * TT + j];

        const int buf = i & 1;
        const float m = s0_sh[buf];          // = s_{i-2}[0] (slots pre-seeded for i=1,2)
        p_sh[buf][j] = __expf(s - m);
        __syncthreads();                      // the ONLY barrier per step

        const v4f* pv = (const v4f*)p_sh[buf];
        v4f a0 = {0,0,0,0}, a1 = {0,0,0,0}, a2 = {0,0,0,0}, a3 = {0,0,0,0};
        v4f a4 = {0,0,0,0}, a5 = {0,0,0,0}, a6 = {0,0,0,0}, a7 = {0,0,0,0};
        a0 = __builtin_elementwise_fma(pv[0],  E0,  a0);
        a1 = __builtin_elementwise_fma(pv[1],  E1,  a1);
        a2 = __builtin_elementwise_fma(pv[2],  E2,  a2);
        a3 = __builtin_elementwise_fma(pv[3],  E3,  a3);
        a4 = __builtin_elementwise_fma(pv[4],  E4,  a4);
        a5 = __builtin_elementwise_fma(pv[5],  E5,  a5);
        a6 = __builtin_elementwise_fma(pv[6],  E6,  a6);
        a7 = __builtin_elementwise_fma(pv[7],  E7,  a7);
        a0 = __builtin_elementwise_fma(pv[8],  E8,  a0);
        a1 = __builtin_elementwise_fma(pv[9],  E9,  a1);
        a2 = __builtin_elementwise_fma(pv[10], E10, a2);
        a3 = __builtin_elementwise_fma(pv[11], E11, a3);
        a4 = __builtin_elementwise_fma(pv[12], E12, a4);
        a5 = __builtin_elementwise_fma(pv[13], E13, a5);
        a6 = __builtin_elementwise_fma(pv[14], E14, a6);
        a7 = __builtin_elementwise_fma(pv[15], E15, a7);
        a0 = __builtin_elementwise_fma(pv[16], E16, a0);
        a1 = __builtin_elementwise_fma(pv[17], E17, a1);
        a2 = __builtin_elementwise_fma(pv[18], E18, a2);
        a3 = __builtin_elementwise_fma(pv[19], E19, a3);
        a4 = __builtin_elementwise_fma(pv[20], E20, a4);
        a5 = __builtin_elementwise_fma(pv[21], E21, a5);
        a6 = __builtin_elementwise_fma(pv[22], E22, a6);
        a7 = __builtin_elementwise_fma(pv[23], E23, a7);
        a0 = __builtin_elementwise_fma(pv[24], E24, a0);
        a1 = __builtin_elementwise_fma(pv[25], E25, a1);
        a2 = __builtin_elementwise_fma(pv[26], E26, a2);
        a3 = __builtin_elementwise_fma(pv[27], E27, a3);
        a4 = __builtin_elementwise_fma(pv[28], E28, a4);
        a5 = __builtin_elementwise_fma(pv[29], E29, a5);
        a6 = __builtin_elementwise_fma(pv[30], E30, a6);
        a7 = __builtin_elementwise_fma(pv[31], E31, a7);
        v4f t0 = a0 + a4, t1 = a1 + a5, t2 = a2 + a6, t3 = a3 + a7;
        v4f tt = (t0 + t2) + (t1 + t3);
        const float acc = (tt.x + tt.y) + (tt.z + tt.w);

        const float snew = em_cur + m + cj + __logf(acc);
        s = (mask_sh[i] > 0) ? snew : s;
        if (j == 0) s0_sh[buf] = s;          // consumed at step i+2 (fenced by step i+1's barrier)
    }

    // den = logsumexp_j(s[j] + end[j])
    float v = s + endt[j];
    float m2 = v;
    #pragma unroll
    for (int off = 32; off; off >>= 1) m2 = fmaxf(m2, __shfl_xor(m2, off));
    if (lane == 0) red2[wave] = m2;
    __syncthreads();
    m2 = fmaxf(red2[0], red2[1]);
    float e = __expf(v - m2);
    #pragma unroll
    for (int off = 32; off; off >>= 1) e += __shfl_xor(e, off);
    if (lane == 0) red[wave] = e;
    __syncthreads();
    if (j == 0) den_out[b] = m2 + __logf(red[0] + red[1]);
}

// ---------------- final: out = sum_b (den_b - num_b) ----------------
__global__ void crf_final_kernel(const float* __restrict__ den,
                                 const float* __restrict__ num,
                                 float* __restrict__ out)
{
    int t = threadIdx.x;   // 64 threads == BB
    float v = den[t] - num[t];
    #pragma unroll
    for (int off = 32; off; off >>= 1) v += __shfl_xor(v, off);
    if (t == 0) out[0] = v;
}

extern "C" void kernel_launch(void* const* d_in, const int* in_sizes, int n_in,
                              void* d_out, int out_size, void* d_ws, size_t ws_size,
                              hipStream_t stream)
{
    const float* em    = (const float*)d_in[0];   // [B,L,T] f32
    const int*   tgt   = (const int*)d_in[1];     // [B,L]
    const int*   mask  = (const int*)d_in[2];     // [B,L]
    const float* start = (const float*)d_in[3];   // [T]
    const float* endt  = (const float*)d_in[4];   // [T]
    const float* trans = (const float*)d_in[5];   // [T,T]
    float* out = (float*)d_out;

    float* den = (float*)d_ws;        // BB floats
    float* num = den + BB;            // BB floats

    crf_num_kernel<<<BB, 256, 0, stream>>>(em, tgt, mask, start, endt, trans, num);
    crf_forward_kernel<<<BB, 128, 0, stream>>>(em, mask, start, endt, trans, den);
    crf_final_kernel<<<1, 64, 0, stream>>>(den, num, out);
}

// Round 4
// 926.283 us; speedup vs baseline: 2.0367x; 1.3662x over previous
//
#include <hip/hip_runtime.h>

#define BB 64
#define LL 2048
#define TT 128

typedef float v4f __attribute__((ext_vector_type(4)));

// ---------------- numerator: gold path score per batch ----------------
__global__ __launch_bounds__(256) void crf_num_kernel(
    const float* __restrict__ em, const int* __restrict__ tgt,
    const int* __restrict__ mask, const float* __restrict__ start,
    const float* __restrict__ endt, const float* __restrict__ trans,
    float* __restrict__ num_out)
{
    const int b = blockIdx.x;
    const int t = threadIdx.x;
    const int wave = t >> 6, lane = t & 63;
    const float* emb = em + (size_t)b * LL * TT;
    const int* tb = tgt + (size_t)b * LL;
    const int* mb = mask + (size_t)b * LL;

    float acc = 0.f;
    int msum = 0;
    for (int l = t; l < LL; l += 256) {
        int mv = mb[l];
        msum += mv;
        if (l >= 1 && mv > 0) {
            int tp = tb[l - 1], tc = tb[l];
            acc += trans[tp * TT + tc] + emb[(size_t)l * TT + tc];
        }
    }
    __shared__ float sacc[4];
    __shared__ int smsum[4];
    #pragma unroll
    for (int off = 32; off; off >>= 1) {
        acc += __shfl_xor(acc, off);
        msum += __shfl_xor(msum, off);
    }
    if (lane == 0) { sacc[wave] = acc; smsum[wave] = msum; }
    __syncthreads();
    if (t == 0) {
        float tot = sacc[0] + sacc[1] + sacc[2] + sacc[3];
        int total_mask = smsum[0] + smsum[1] + smsum[2] + smsum[3];
        int t0 = tb[0];
        tot += start[t0] + emb[t0];
        int se = total_mask - 1;
        int lt = tb[se];
        tot += endt[lt];
        num_out[b] = tot;
    }
}

// ---------------- denominator: forward algorithm, 1 block per batch ----------------
// 256 threads: thread t owns tag j = t>>1 and K-half h = t&1 (64 k-values each,
// 16 v4f of E per thread -> fits the allocator's VGPR budget, no scratch reload).
// Halves combine via __shfl_xor(partial, 1) (adjacent lane, same wave) -> still
// exactly ONE barrier per step. Offset m = s_{i-2}[0] via lag-2 LDS broadcast.
__global__ __launch_bounds__(256, 1) __attribute__((amdgpu_waves_per_eu(1, 2)))
void crf_forward_kernel(
    const float* __restrict__ em, const int* __restrict__ mask,
    const float* __restrict__ start, const float* __restrict__ endt,
    const float* __restrict__ trans, float* __restrict__ den_out)
{
    const int b = blockIdx.x;
    const int t = threadIdx.x;        // 0..255
    const int j = t >> 1;             // tag 0..127
    const int h = t & 1;              // k-half
    const int wave = t >> 6, lane = t & 63;

    __shared__ __align__(16) float p_sh[2][TT];   // double-buffered exp(s-m)
    __shared__ float s0_sh[2];                    // lag-2 offset slots
    __shared__ int mask_sh[LL];
    __shared__ float red[4], red2[4];

    const float* emb = em + (size_t)b * LL * TT;
    const int* mb = mask + (size_t)b * LL;

    for (int l = t; l < LL; l += 256) mask_sh[l] = mb[l];

    // column max over FULL k (both halves must use the same c_j)
    float cj = -1e30f;
    for (int k = 0; k < TT; ++k) cj = fmaxf(cj, trans[k * TT + j]);

    const int kbase = h << 6;   // 0 or 64

#define EINIT(n) const v4f E##n = { \
    __expf(trans[(kbase + 4*(n) + 0) * TT + j] - cj), \
    __expf(trans[(kbase + 4*(n) + 1) * TT + j] - cj), \
    __expf(trans[(kbase + 4*(n) + 2) * TT + j] - cj), \
    __expf(trans[(kbase + 4*(n) + 3) * TT + j] - cj) };
    EINIT(0)  EINIT(1)  EINIT(2)  EINIT(3)
    EINIT(4)  EINIT(5)  EINIT(6)  EINIT(7)
    EINIT(8)  EINIT(9)  EINIT(10) EINIT(11)
    EINIT(12) EINIT(13) EINIT(14) EINIT(15)
#undef EINIT

    float s = start[j] + emb[j];
    if (t == 0) { s0_sh[0] = s; s0_sh[1] = s; }
    __syncthreads();   // fences mask_sh + s0_sh init

    // 4-deep rolling prefetch of emission values (per-thread scalar)
    float emA = emb[(size_t)1 * TT + j];
    float emB = emb[(size_t)2 * TT + j];
    float emC = emb[(size_t)3 * TT + j];
    float emD = emb[(size_t)4 * TT + j];

    #pragma unroll 2
    for (int i = 1; i < LL; ++i) {
        const float em_cur = emA;
        emA = emB; emB = emC; emC = emD;
        if (i + 4 < LL) emD = emb[(size_t)(i + 4) * TT + j];

        const int buf = i & 1;
        const float m = s0_sh[buf];          // = s_{i-2}[0] (broadcast read)
        const float p = __expf(s - m);
        if (h == 0) p_sh[buf][j] = p;
        __syncthreads();                     // the ONLY barrier per step

        const v4f* pv = (const v4f*)(&p_sh[buf][kbase]);
        v4f a0 = {0,0,0,0}, a1 = {0,0,0,0}, a2 = {0,0,0,0}, a3 = {0,0,0,0};
        a0 = __builtin_elementwise_fma(pv[0],  E0,  a0);
        a1 = __builtin_elementwise_fma(pv[1],  E1,  a1);
        a2 = __builtin_elementwise_fma(pv[2],  E2,  a2);
        a3 = __builtin_elementwise_fma(pv[3],  E3,  a3);
        a0 = __builtin_elementwise_fma(pv[4],  E4,  a0);
        a1 = __builtin_elementwise_fma(pv[5],  E5,  a1);
        a2 = __builtin_elementwise_fma(pv[6],  E6,  a2);
        a3 = __builtin_elementwise_fma(pv[7],  E7,  a3);
        a0 = __builtin_elementwise_fma(pv[8],  E8,  a0);
        a1 = __builtin_elementwise_fma(pv[9],  E9,  a1);
        a2 = __builtin_elementwise_fma(pv[10], E10, a2);
        a3 = __builtin_elementwise_fma(pv[11], E11, a3);
        a0 = __builtin_elementwise_fma(pv[12], E12, a0);
        a1 = __builtin_elementwise_fma(pv[13], E13, a1);
        a2 = __builtin_elementwise_fma(pv[14], E14, a2);
        a3 = __builtin_elementwise_fma(pv[15], E15, a3);
        v4f tt4 = (a0 + a2) + (a1 + a3);
        const float partial = (tt4.x + tt4.y) + (tt4.z + tt4.w);
        const float acc = partial + __shfl_xor(partial, 1);   // combine K-halves

        const float snew = em_cur + m + cj + __logf(acc);
        s = (mask_sh[i] > 0) ? snew : s;
        if (t == 0) s0_sh[buf] = s;          // consumed at step i+2
    }

    // den = logsumexp_j(s[j] + end[j]); h==1 threads hold duplicate s[j]
    float v = s + endt[j];
    float m2 = v;
    #pragma unroll
    for (int off = 32; off; off >>= 1) m2 = fmaxf(m2, __shfl_xor(m2, off));
    if (lane == 0) red2[wave] = m2;
    __syncthreads();
    m2 = fmaxf(fmaxf(red2[0], red2[1]), fmaxf(red2[2], red2[3]));
    float e = (h == 0) ? __expf(v - m2) : 0.f;   // count each tag once
    #pragma unroll
    for (int off = 32; off; off >>= 1) e += __shfl_xor(e, off);
    if (lane == 0) red[wave] = e;
    __syncthreads();
    if (t == 0) den_out[b] = m2 + __logf(red[0] + red[1] + red[2] + red[3]);
}

// ---------------- final: out = sum_b (den_b - num_b) ----------------
__global__ void crf_final_kernel(const float* __restrict__ den,
                                 const float* __restrict__ num,
                                 float* __restrict__ out)
{
    int t = threadIdx.x;   // 64 threads == BB
    float v = den[t] - num[t];
    #pragma unroll
    for (int off = 32; off; off >>= 1) v += __shfl_xor(v, off);
    if (t == 0) out[0] = v;
}

extern "C" void kernel_launch(void* const* d_in, const int* in_sizes, int n_in,
                              void* d_out, int out_size, void* d_ws, size_t ws_size,
                              hipStream_t stream)
{
    const float* em    = (const float*)d_in[0];   // [B,L,T] f32
    const int*   tgt   = (const int*)d_in[1];     // [B,L]
    const int*   mask  = (const int*)d_in[2];     // [B,L]
    const float* start = (const float*)d_in[3];   // [T]
    const float* endt  = (const float*)d_in[4];   // [T]
    const float* trans = (const float*)d_in[5];   // [T,T]
    float* out = (float*)d_out;

    float* den = (float*)d_ws;        // BB floats
    float* num = den + BB;            // BB floats

    crf_num_kernel<<<BB, 256, 0, stream>>>(em, tgt, mask, start, endt, trans, num);
    crf_forward_kernel<<<BB, 256, 0, stream>>>(em, mask, start, endt, trans, den);
    crf_final_kernel<<<1, 64, 0, stream>>>(den, num, out);
}